// Round 1
// baseline (815.231 us; speedup 1.0000x reference)
//
#include <hip/hip_runtime.h>
#include <hip/hip_bf16.h>

#define N_NODES 100000
#define N_EDGES 3200000
#define IN_DIM  512
#define HIDDEN  16
#define NCLS    7

// ---------------- degree ----------------
__global__ void k_init_deg(unsigned int* __restrict__ deg) {
    int i = blockIdx.x * 256 + threadIdx.x;
    if (i < N_NODES) deg[i] = 1u;   // self-loop contributes 1
}

__global__ void k_count_deg(const int* __restrict__ dst, unsigned int* __restrict__ deg) {
    int e = blockIdx.x * 256 + threadIdx.x;
    if (e < N_EDGES) atomicAdd(&deg[dst[e]], 1u);
}

// ---------------- layer-1 GEMM: h1 = x @ W1, plus dinv + self-loop init ----------------
// 256 nodes per block, K staged through LDS in 32-wide chunks (stride 33 pad).
__global__ __launch_bounds__(256) void k_gemm1(
    const float* __restrict__ x, const float* __restrict__ W1,
    const unsigned int* __restrict__ deg,
    float* __restrict__ dinv, float* __restrict__ h1, float* __restrict__ agg1) {
    __shared__ float Xs[256 * 33];
    const int tid = threadIdx.x;
    const int n0  = blockIdx.x * 256;
    const int n   = n0 + tid;

    float acc[16];
#pragma unroll
    for (int j = 0; j < 16; ++j) acc[j] = 0.f;

    for (int kc = 0; kc < IN_DIM; kc += 32) {
        __syncthreads();
        // cooperative coalesced load: 256 rows x 32 floats = 2048 float4
#pragma unroll
        for (int r = 0; r < 8; ++r) {
            int flat = r * 256 + tid;       // float4 index 0..2047
            int row  = flat >> 3;           // node within tile
            int col  = (flat & 7) << 2;     // float column
            int gn   = n0 + row;
            if (gn < N_NODES) {
                const float4 v = *(const float4*)(x + (size_t)gn * IN_DIM + kc + col);
                float* d = &Xs[row * 33 + col];
                d[0] = v.x; d[1] = v.y; d[2] = v.z; d[3] = v.w;
            }
        }
        __syncthreads();
        if (n < N_NODES) {
#pragma unroll
            for (int i = 0; i < 32; ++i) {
                float xv = Xs[tid * 33 + i];
                const float* wr = W1 + (size_t)(kc + i) * 16;  // wave-uniform -> s_load
#pragma unroll
                for (int j = 0; j < 16; ++j) acc[j] = fmaf(xv, wr[j], acc[j]);
            }
        }
    }

    if (n < N_NODES) {
        float di = rsqrtf((float)deg[n]);
        dinv[n] = di;
        float w = di * di;                  // self-loop norm
#pragma unroll
        for (int j = 0; j < 16; j += 4) {
            float4 hv = make_float4(acc[j], acc[j+1], acc[j+2], acc[j+3]);
            *(float4*)(h1 + (size_t)n * 16 + j) = hv;
            *(float4*)(agg1 + (size_t)n * 16 + j) =
                make_float4(hv.x * w, hv.y * w, hv.z * w, hv.w * w);
        }
    }
}

// ---------------- layer-1 edge aggregation: 16 lanes per edge ----------------
__global__ __launch_bounds__(256) void k_edge1(
    const int* __restrict__ src, const int* __restrict__ dst,
    const float* __restrict__ dinv, const float* __restrict__ h1,
    float* __restrict__ agg1) {
    int gid = blockIdx.x * 256 + threadIdx.x;
    int e = gid >> 4;
    int j = gid & 15;
    if (e >= N_EDGES) return;
    int s = src[e], d = dst[e];
    float w = dinv[s] * dinv[d];
    float val = h1[(size_t)s * 16 + j] * w;
    unsafeAtomicAdd(&agg1[(size_t)d * 16 + j], val);
}

// ---------------- relu(agg1+b1) @ W2 -> h2 (padded stride 8), + self-loop init ----------------
__global__ __launch_bounds__(256) void k_layer2(
    const float* __restrict__ agg1, const float* __restrict__ b1,
    const float* __restrict__ W2, const float* __restrict__ dinv,
    float* __restrict__ h2, float* __restrict__ agg2) {
    int n = blockIdx.x * 256 + threadIdx.x;
    if (n >= N_NODES) return;
    float z[16];
#pragma unroll
    for (int k = 0; k < 16; k += 4) {
        float4 v = *(const float4*)(agg1 + (size_t)n * 16 + k);
        z[k]   = fmaxf(v.x + b1[k],   0.f);
        z[k+1] = fmaxf(v.y + b1[k+1], 0.f);
        z[k+2] = fmaxf(v.z + b1[k+2], 0.f);
        z[k+3] = fmaxf(v.w + b1[k+3], 0.f);
    }
    float di = dinv[n];
    float w  = di * di;
    float o[8];
#pragma unroll
    for (int j = 0; j < 7; ++j) {
        float a = 0.f;
#pragma unroll
        for (int k = 0; k < 16; ++k) a = fmaf(z[k], W2[k * 7 + j], a);
        o[j] = a;
    }
    o[7] = 0.f;
#pragma unroll
    for (int j = 0; j < 8; j += 4) {
        *(float4*)(h2   + (size_t)n * 8 + j) = make_float4(o[j], o[j+1], o[j+2], o[j+3]);
        *(float4*)(agg2 + (size_t)n * 8 + j) =
            make_float4(o[j] * w, o[j+1] * w, o[j+2] * w, o[j+3] * w);
    }
}

// ---------------- layer-2 edge aggregation: 8 lanes per edge (j<7 active) ----------------
__global__ __launch_bounds__(256) void k_edge2(
    const int* __restrict__ src, const int* __restrict__ dst,
    const float* __restrict__ dinv, const float* __restrict__ h2,
    float* __restrict__ agg2) {
    int gid = blockIdx.x * 256 + threadIdx.x;
    int e = gid >> 3;
    int j = gid & 7;
    if (e >= N_EDGES || j >= 7) return;
    int s = src[e], d = dst[e];
    float w = dinv[s] * dinv[d];
    unsafeAtomicAdd(&agg2[(size_t)d * 8 + j], h2[(size_t)s * 8 + j] * w);
}

// ---------------- bias + log_softmax ----------------
__global__ __launch_bounds__(256) void k_lsm(
    const float* __restrict__ agg2, const float* __restrict__ b2,
    float* __restrict__ out) {
    int n = blockIdx.x * 256 + threadIdx.x;
    if (n >= N_NODES) return;
    float v[7];
    float m = -1e30f;
#pragma unroll
    for (int j = 0; j < 7; ++j) {
        v[j] = agg2[(size_t)n * 8 + j] + b2[j];
        m = fmaxf(m, v[j]);
    }
    float s = 0.f;
#pragma unroll
    for (int j = 0; j < 7; ++j) s += expf(v[j] - m);
    float ls = logf(s) + m;
#pragma unroll
    for (int j = 0; j < 7; ++j) out[(size_t)n * 7 + j] = v[j] - ls;
}

extern "C" void kernel_launch(void* const* d_in, const int* in_sizes, int n_in,
                              void* d_out, int out_size, void* d_ws, size_t ws_size,
                              hipStream_t stream) {
    const float* x  = (const float*)d_in[0];
    const int*   ei = (const int*)d_in[1];
    const float* W1 = (const float*)d_in[2];
    const float* b1 = (const float*)d_in[3];
    const float* W2 = (const float*)d_in[4];
    const float* b2 = (const float*)d_in[5];
    float* out = (float*)d_out;

    const int* src = ei;             // edge_index[0]
    const int* dst = ei + N_EDGES;   // edge_index[1]

    char* ws = (char*)d_ws;
    size_t o = 0;
    auto alloc = [&](size_t bytes) -> void* {
        void* p = ws + o;
        o = (o + bytes + 255) & ~(size_t)255;
        return p;
    };
    unsigned int* deg  = (unsigned int*)alloc((size_t)N_NODES * 4);
    float*        dinv = (float*)alloc((size_t)N_NODES * 4);
    float*        h1   = (float*)alloc((size_t)N_NODES * 16 * 4);
    float*        agg1 = (float*)alloc((size_t)N_NODES * 16 * 4);
    float*        h2   = (float*)alloc((size_t)N_NODES * 8 * 4);
    float*        agg2 = (float*)alloc((size_t)N_NODES * 8 * 4);

    const int nb_n = (N_NODES + 255) / 256;
    k_init_deg <<<nb_n, 256, 0, stream>>>(deg);
    k_count_deg<<<(N_EDGES + 255) / 256, 256, 0, stream>>>(dst, deg);
    k_gemm1    <<<nb_n, 256, 0, stream>>>(x, W1, deg, dinv, h1, agg1);
    k_edge1    <<<(N_EDGES * 16 + 255) / 256, 256, 0, stream>>>(src, dst, dinv, h1, agg1);
    k_layer2   <<<nb_n, 256, 0, stream>>>(agg1, b1, W2, dinv, h2, agg2);
    k_edge2    <<<(N_EDGES * 8 + 255) / 256, 256, 0, stream>>>(src, dst, dinv, h2, agg2);
    k_lsm      <<<nb_n, 256, 0, stream>>>(agg2, b2, out);
}